// Round 7
// baseline (385.004 us; speedup 1.0000x reference)
//
#include <hip/hip_runtime.h>
#include <hip/hip_bf16.h>
#include <math.h>

#define TT 32
#define NN 2048
#define FF 64

typedef float f32x4 __attribute__((ext_vector_type(4)));
typedef __bf16 bf16x8 __attribute__((ext_vector_type(8)));
typedef unsigned short u16x8 __attribute__((ext_vector_type(8)));

__device__ __forceinline__ unsigned short f2bf(float f) {
    __bf16 h = (__bf16)f;
    return __builtin_bit_cast(unsigned short, h);
}

// ---------------------------------------------------------------------------
// K_A: per-timestep scores (fp64) + top-64 (desc, min-index tie-break) +
// z^T[t][j][f] = X[idx_j][f] * tanh(val_j).  grid = T, 256 threads.
// ---------------------------------------------------------------------------
__global__ __launch_bounds__(256) void topk_kernel(
    const float* __restrict__ X, const float* __restrict__ mask,
    const float* __restrict__ scorer, float* __restrict__ zt)
{
    const int t = blockIdx.x, tid = threadIdx.x;
    __shared__ double svals[64];
    __shared__ int    sidx[64];
    __shared__ double swv[4];
    __shared__ int    swi[4];

    float sc[64];
#pragma unroll
    for (int f = 0; f < 64; f += 4) {
        float4 v = *(const float4*)(scorer + f);
        sc[f] = v.x; sc[f+1] = v.y; sc[f+2] = v.z; sc[f+3] = v.w;
    }
    double nrm = 0.0;
#pragma unroll
    for (int f = 0; f < 64; ++f) nrm += (double)sc[f] * (double)sc[f];
    const double inv = 1.0 / sqrt(nrm);

    const float* Xt = X + (size_t)t * NN * FF;
    double ls[8];
#pragma unroll
    for (int e = 0; e < 8; ++e) {
        const int n = e * 256 + tid;
        const float* xr = Xt + (size_t)n * FF;
        double s = 0.0;
#pragma unroll
        for (int f = 0; f < 64; f += 4) {
            float4 v = *(const float4*)(xr + f);
            s += (double)v.x * (double)sc[f]   + (double)v.y * (double)sc[f+1]
               + (double)v.z * (double)sc[f+2] + (double)v.w * (double)sc[f+3];
        }
        ls[e] = s * inv + (double)mask[t * NN + n];
    }

    const int lane = tid & 63, w = tid >> 6;
    for (int r = 0; r < 64; ++r) {
        double bv = ls[0]; int bi = tid;
#pragma unroll
        for (int e = 1; e < 8; ++e) {
            const int n = e * 256 + tid;
            if (ls[e] > bv) { bv = ls[e]; bi = n; }
        }
#pragma unroll
        for (int off = 1; off < 64; off <<= 1) {
            double ov = __shfl_xor(bv, off);
            int    oi = __shfl_xor(bi, off);
            if (ov > bv || (ov == bv && oi < bi)) { bv = ov; bi = oi; }
        }
        if (lane == 0) { swv[w] = bv; swi[w] = bi; }
        __syncthreads();
        if (tid == 0) {
            double fv = swv[0]; int fi = swi[0];
#pragma unroll
            for (int q = 1; q < 4; ++q)
                if (swv[q] > fv || (swv[q] == fv && swi[q] < fi)) { fv = swv[q]; fi = swi[q]; }
            svals[r] = fv; sidx[r] = fi;
        }
        __syncthreads();
        const int win = sidx[r];
#pragma unroll
        for (int e = 0; e < 8; ++e)
            if (win == e * 256 + tid) ls[e] = -INFINITY;
    }
    __syncthreads();

    const int j = tid >> 2, fg = tid & 3;
    const float th  = tanhf((float)svals[j]);
    const int  idx  = sidx[j];
    const float* xr = Xt + (size_t)idx * FF + fg * 16;
    float* zr = zt + (size_t)t * 4096 + j * 64 + fg * 16;
#pragma unroll
    for (int f = 0; f < 16; f += 4) {
        float4 v = *(const float4*)(xr + f);
        *(float4*)(zr + f) = make_float4(v.x * th, v.y * th, v.z * th, v.w * th);
    }
}

// ---------------------------------------------------------------------------
// K_W: Wz[m][t][i][j] = b_m[i][j] + sum_f W_m[i][f] * z[f][j]
// ---------------------------------------------------------------------------
__global__ __launch_bounds__(256) void wz_kernel(
    const float* __restrict__ zt,
    const float* __restrict__ Wu, const float* __restrict__ bu,
    const float* __restrict__ Wr, const float* __restrict__ br,
    const float* __restrict__ Wh, const float* __restrict__ bh,
    float* __restrict__ Wz)
{
    const int m = blockIdx.x, t = blockIdx.y, tid = threadIdx.x;
    const float* W = (m == 0) ? Wu : (m == 1) ? Wr : Wh;
    const float* b = (m == 0) ? bu : (m == 1) ? br : bh;
    const int j = tid & 63, i0 = (tid >> 6) << 4;

    float zr[64];
    const float* zrow = zt + (size_t)t * 4096 + j * 64;
#pragma unroll
    for (int f = 0; f < 64; f += 4) {
        float4 v = *(const float4*)(zrow + f);
        zr[f] = v.x; zr[f+1] = v.y; zr[f+2] = v.z; zr[f+3] = v.w;
    }
    float* o = Wz + ((size_t)m * TT + t) * 4096;
    for (int i = i0; i < i0 + 16; ++i) {
        float acc = b[i * 64 + j];
#pragma unroll
        for (int f = 0; f < 64; ++f) acc += W[i * 64 + f] * zr[f];
        o[i * 64 + j] = acc;
    }
}

// ---------------------------------------------------------------------------
// K_B: column-separable GRU chain, one Q-column per block.
// ---------------------------------------------------------------------------
__global__ __launch_bounds__(256) void qchain_kernel(
    const float* __restrict__ Q0,
    const float* __restrict__ Uu, const float* __restrict__ Ur, const float* __restrict__ Uh,
    const float* __restrict__ Wz, float* __restrict__ Qseq)
{
    const int j = blockIdx.x, tid = threadIdx.x;
    const int w = tid >> 6, l = tid & 63;
    const int i = (w << 4) + (l & 15);
    const int fq = l >> 4, fb = fq << 4;

    float uu[16], ur[16], uh[16];
#pragma unroll
    for (int e = 0; e < 16; e += 4) {
        float4 a = *(const float4*)(Uu + i * 64 + fb + e);
        uu[e] = a.x; uu[e+1] = a.y; uu[e+2] = a.z; uu[e+3] = a.w;
        float4 c = *(const float4*)(Ur + i * 64 + fb + e);
        ur[e] = c.x; ur[e+1] = c.y; ur[e+2] = c.z; ur[e+3] = c.w;
        float4 d = *(const float4*)(Uh + i * 64 + fb + e);
        uh[e] = d.x; uh[e+1] = d.y; uh[e+2] = d.z; uh[e+3] = d.w;
    }
    __shared__ __align__(16) float q[64];
    __shared__ __align__(16) float rr[64];
    if (tid < 64) q[tid] = Q0[tid * 64 + j];
    __syncthreads();

    const float* WzU = Wz;
    const float* WzR = Wz + (size_t)TT * 4096;
    const float* WzH = Wz + (size_t)2 * TT * 4096;

    for (int t = 0; t < TT; ++t) {
        float q16[16];
#pragma unroll
        for (int e = 0; e < 16; e += 4) {
            f32x4 v = *(const f32x4*)(&q[fb + e]);
            q16[e] = v[0]; q16[e+1] = v[1]; q16[e+2] = v[2]; q16[e+3] = v[3];
        }
        float su = 0.f, sr = 0.f;
#pragma unroll
        for (int e = 0; e < 16; ++e) { su += uu[e] * q16[e]; sr += ur[e] * q16[e]; }
        su += __shfl_xor(su, 16); su += __shfl_xor(su, 32);
        sr += __shfl_xor(sr, 16); sr += __shfl_xor(sr, 32);
        const int off = t * 4096 + i * 64 + j;
        const float u_ = 1.f / (1.f + expf(-(su + WzU[off])));
        const float r_ = 1.f / (1.f + expf(-(sr + WzR[off])));
        if (fq == 0) rr[i] = r_;
        __syncthreads();
        float sh = 0.f;
#pragma unroll
        for (int e = 0; e < 16; e += 4) {
            f32x4 v = *(const f32x4*)(&rr[fb + e]);
            sh += uh[e]   * (v[0] * q16[e]);
            sh += uh[e+1] * (v[1] * q16[e+1]);
            sh += uh[e+2] * (v[2] * q16[e+2]);
            sh += uh[e+3] * (v[3] * q16[e+3]);
        }
        sh += __shfl_xor(sh, 16); sh += __shfl_xor(sh, 32);
        float hv = sh + WzH[off];
        hv = hv > 0.f ? hv : 0.f;
        const float qi = q[i];
        const float qn = (1.f - u_) * qi + u_ * hv;
        __syncthreads();
        if (fq == 0) {
            q[i] = qn;
            Qseq[(size_t)t * 4096 + i * 64 + j] = qn;
        }
        __syncthreads();
    }
}

// ---------------------------------------------------------------------------
// K_C: Ytr[t][j][n] = bf16( sum_f X[t][n][f] * Qseq[t][f][j] )
// v2: LDS transpose so global stores are 16B contiguous per lane.
// ---------------------------------------------------------------------------
__global__ __launch_bounds__(256) void y_kernel(
    const float* __restrict__ X, const float* __restrict__ Qseq,
    unsigned short* __restrict__ Ytr)
{
    const int t = blockIdx.y, tid = threadIdx.x;
    const int n0 = blockIdx.x * 256;
    const int n = n0 + tid;
    __shared__ __align__(16) float Qs[4096];
    __shared__ __align__(16) unsigned short Ys[64][264];  // [j][local n], padded
    for (int c = tid; c < 4096; c += 256) Qs[c] = Qseq[(size_t)t * 4096 + c];
    __syncthreads();

    const float* xr = X + ((size_t)t * NN + n) * FF;
    float y[64];
#pragma unroll
    for (int jj = 0; jj < 64; ++jj) y[jj] = 0.f;
    for (int f4 = 0; f4 < 64; f4 += 4) {
        float4 xv = *(const float4*)(xr + f4);
        float xa[4] = {xv.x, xv.y, xv.z, xv.w};
#pragma unroll
        for (int ff = 0; ff < 4; ++ff) {
            const float xf = xa[ff];
            const float* qr = &Qs[(f4 + ff) << 6];
#pragma unroll
            for (int jj = 0; jj < 64; jj += 4) {
                f32x4 qv = *(const f32x4*)(qr + jj);
                y[jj]   += xf * qv[0];
                y[jj+1] += xf * qv[1];
                y[jj+2] += xf * qv[2];
                y[jj+3] += xf * qv[3];
            }
        }
    }
#pragma unroll
    for (int jj = 0; jj < 64; ++jj) Ys[jj][tid] = f2bf(y[jj]);
    __syncthreads();

    // write out: thread -> j = tid>>2, 64 consecutive n starting at (tid&3)*64
    const int j = tid >> 2, nc = (tid & 3) << 6;
    unsigned short* yo = Ytr + (size_t)t * FF * NN + (size_t)j * NN + n0 + nc;
#pragma unroll
    for (int c = 0; c < 8; ++c)
        *(u16x8*)(yo + c * 8) = *(const u16x8*)(&Ys[j][nc + c * 8]);
}

// ---------------------------------------------------------------------------
// K_D: out[t] = relu(A[t] @ Y[t]).  DRAM-page-friendly MFMA GEMM:
// tile M=64 x N=64, BK=256. A staged f32 via global_load_lds where ONE
// wave-instr stages ONE FULL 1KB row segment (64 lanes x 16B contiguous)
// -> DRAM sees 1KB sequential chunks instead of 256B. Double-buffered
// (2 x 64KB LDS). B (Ytr, XCD-L2-resident) read directly from L2 as
// MFMA fragments -- no B staging. A chunk-XOR swizzle via pre-swizzled
// global source + swizzled ds_read (rule #21). 1024 blocks XCD-grouped.
// ---------------------------------------------------------------------------
__global__ __launch_bounds__(256) void gemm_kernel(
    const float* __restrict__ A, const unsigned short* __restrict__ Ytr,
    float* __restrict__ out)
{
    __shared__ __align__(16) unsigned char Abuf[2][65536];  // f32 [64 r][256 k]
    const int tid = threadIdx.x;
    const int bid = blockIdx.x;
    const int xcd = bid & 7, li = bid >> 3;          // 8 XCDs x 128 blocks
    const int t = (xcd << 2) + (li >> 5);            // 4 timesteps per XCD
    const int m0 = (li & 31) * 64;
    const int lane = tid & 63, w = tid >> 6;
    const int lr = lane & 15, lq = lane >> 4;

    const float* Ap = A + (size_t)t * NN * NN + (size_t)m0 * NN;
    const unsigned short* Yp = Ytr + (size_t)t * FF * NN;

    // B fragment row pointers (direct from L2): j = nt*16 + lr, k-octet lq*8
    const unsigned short* brow[4];
#pragma unroll
    for (int nt = 0; nt < 4; ++nt)
        brow[nt] = Yp + (size_t)((nt << 4) + lr) * NN + (lq << 3);

    // STAGE: wave w stages its own 16 rows (w*16+q); one instr = one row's
    // 1KB segment. Global chunk pre-swizzled: lane ^ (row&7).
#define STAGE(sel, kk)                                                          \
    {                                                                           \
        _Pragma("unroll")                                                       \
        for (int q = 0; q < 16; ++q) {                                          \
            const int row = (w << 4) + q;                                       \
            const float* g = Ap + (size_t)row * NN + (kk)                       \
                           + ((lane ^ (q & 7)) << 2);                           \
            __builtin_amdgcn_global_load_lds(                                   \
                (const __attribute__((address_space(1))) void*)g,               \
                (__attribute__((address_space(3))) void*)                       \
                    (&Abuf[sel][row << 10]), 16, 0, 0);                         \
        }                                                                       \
    }

    // COMPUTE: 8 ks of K=32.  A-frag: row = w*16+lr, chunks swizzled by lr&7.
#define COMPUTE(sel, kk)                                                        \
    {                                                                           \
        _Pragma("unroll")                                                       \
        for (int ks = 0; ks < 8; ++ks) {                                        \
            const int r = (w << 4) + lr;                                        \
            const int c0 = (ks << 3) + (lq << 1);                               \
            const f32x4 a0 = *(const f32x4*)(                                   \
                Abuf[sel] + (r << 10) + ((c0 ^ (lr & 7)) << 4));                \
            const f32x4 a1 = *(const f32x4*)(                                   \
                Abuf[sel] + (r << 10) + (((c0 + 1) ^ (lr & 7)) << 4));          \
            bf16x8 af;                                                          \
            af[0] = (__bf16)a0[0]; af[1] = (__bf16)a0[1];                       \
            af[2] = (__bf16)a0[2]; af[3] = (__bf16)a0[3];                       \
            af[4] = (__bf16)a1[0]; af[5] = (__bf16)a1[1];                       \
            af[6] = (__bf16)a1[2]; af[7] = (__bf16)a1[3];                       \
            _Pragma("unroll")                                                   \
            for (int nt = 0; nt < 4; ++nt) {                                    \
                const bf16x8 bf = __builtin_bit_cast(bf16x8,                    \
                    *(const uint4*)(brow[nt] + (kk) + (ks << 5)));              \
                acc[nt] = __builtin_amdgcn_mfma_f32_16x16x32_bf16(              \
                    af, bf, acc[nt], 0, 0, 0);                                  \
            }                                                                   \
        }                                                                       \
    }

    f32x4 acc[4];
#pragma unroll
    for (int nt = 0; nt < 4; ++nt) acc[nt] = (f32x4){0.f, 0.f, 0.f, 0.f};

    STAGE(0, 0);
    __syncthreads();
    for (int kt = 0; kt < 7; ++kt) {
        if ((kt & 1) == 0) { STAGE(1, (kt + 1) << 8); COMPUTE(0, kt << 8); }
        else               { STAGE(0, (kt + 1) << 8); COMPUTE(1, kt << 8); }
        __syncthreads();
    }
    COMPUTE(1, 7 << 8);

    // store: D col = lane&15, rows = lq*4 + rg (within wave's 16 rows)
#pragma unroll
    for (int nt = 0; nt < 4; ++nt) {
        const int row0 = m0 + (w << 4) + (lq << 2);
        const int col = (nt << 4) + lr;
#pragma unroll
        for (int rg = 0; rg < 4; ++rg) {
            const float v = acc[nt][rg];
            out[((size_t)t * NN + (row0 + rg)) * FF + col] = v > 0.f ? v : 0.f;
        }
    }
#undef STAGE
#undef COMPUTE
}

// ---------------------------------------------------------------------------
extern "C" void kernel_launch(void* const* d_in, const int* in_sizes, int n_in,
                              void* d_out, int out_size, void* d_ws, size_t ws_size,
                              hipStream_t stream) {
    const float* A      = (const float*)d_in[0];
    const float* X      = (const float*)d_in[1];
    const float* mask   = (const float*)d_in[2];
    const float* Q0     = (const float*)d_in[3];
    const float* scorer = (const float*)d_in[4];
    const float* Wu     = (const float*)d_in[5];
    const float* Uu     = (const float*)d_in[6];
    const float* bu     = (const float*)d_in[7];
    const float* Wr     = (const float*)d_in[8];
    const float* Ur     = (const float*)d_in[9];
    const float* br     = (const float*)d_in[10];
    const float* Wh     = (const float*)d_in[11];
    const float* Uh     = (const float*)d_in[12];
    const float* bh     = (const float*)d_in[13];
    float* out = (float*)d_out;

    float* ws   = (float*)d_ws;
    float* zt   = ws;              // [T][64][64]
    float* Wz   = ws + 131072;     // [3][T][64][64]
    float* Qseq = ws + 524288;     // [T][64][64]
    unsigned short* Ytr = (unsigned short*)(ws + 655360);  // [T][64][2048] bf16

    topk_kernel<<<TT, 256, 0, stream>>>(X, mask, scorer, zt);
    wz_kernel<<<dim3(3, TT), 256, 0, stream>>>(zt, Wu, bu, Wr, br, Wh, bh, Wz);
    qchain_kernel<<<FF, 256, 0, stream>>>(Q0, Uu, Ur, Uh, Wz, Qseq);
    y_kernel<<<dim3(NN / 256, TT), 256, 0, stream>>>(X, Qseq, Ytr);
    gemm_kernel<<<1024, 256, 0, stream>>>(A, Ytr, out);
}

// Round 8
// 367.126 us; speedup vs baseline: 1.0487x; 1.0487x over previous
//
#include <hip/hip_runtime.h>
#include <hip/hip_bf16.h>
#include <math.h>

#define TT 32
#define NN 2048
#define FF 64

typedef float f32x4 __attribute__((ext_vector_type(4)));
typedef __bf16 bf16x8 __attribute__((ext_vector_type(8)));
typedef unsigned short u16x8 __attribute__((ext_vector_type(8)));

__device__ __forceinline__ unsigned short f2bf(float f) {
    __bf16 h = (__bf16)f;
    return __builtin_bit_cast(unsigned short, h);
}

// ---------------------------------------------------------------------------
// K_A: per-timestep scores (fp64) + top-64 (desc, min-index tie-break) +
// z^T[t][j][f] = X[idx_j][f] * tanh(val_j).  grid = T, 256 threads.
// ---------------------------------------------------------------------------
__global__ __launch_bounds__(256) void topk_kernel(
    const float* __restrict__ X, const float* __restrict__ mask,
    const float* __restrict__ scorer, float* __restrict__ zt)
{
    const int t = blockIdx.x, tid = threadIdx.x;
    __shared__ double svals[64];
    __shared__ int    sidx[64];
    __shared__ double swv[4];
    __shared__ int    swi[4];

    float sc[64];
#pragma unroll
    for (int f = 0; f < 64; f += 4) {
        float4 v = *(const float4*)(scorer + f);
        sc[f] = v.x; sc[f+1] = v.y; sc[f+2] = v.z; sc[f+3] = v.w;
    }
    double nrm = 0.0;
#pragma unroll
    for (int f = 0; f < 64; ++f) nrm += (double)sc[f] * (double)sc[f];
    const double inv = 1.0 / sqrt(nrm);

    const float* Xt = X + (size_t)t * NN * FF;
    double ls[8];
#pragma unroll
    for (int e = 0; e < 8; ++e) {
        const int n = e * 256 + tid;
        const float* xr = Xt + (size_t)n * FF;
        double s = 0.0;
#pragma unroll
        for (int f = 0; f < 64; f += 4) {
            float4 v = *(const float4*)(xr + f);
            s += (double)v.x * (double)sc[f]   + (double)v.y * (double)sc[f+1]
               + (double)v.z * (double)sc[f+2] + (double)v.w * (double)sc[f+3];
        }
        ls[e] = s * inv + (double)mask[t * NN + n];
    }

    const int lane = tid & 63, w = tid >> 6;
    for (int r = 0; r < 64; ++r) {
        double bv = ls[0]; int bi = tid;
#pragma unroll
        for (int e = 1; e < 8; ++e) {
            const int n = e * 256 + tid;
            if (ls[e] > bv) { bv = ls[e]; bi = n; }
        }
#pragma unroll
        for (int off = 1; off < 64; off <<= 1) {
            double ov = __shfl_xor(bv, off);
            int    oi = __shfl_xor(bi, off);
            if (ov > bv || (ov == bv && oi < bi)) { bv = ov; bi = oi; }
        }
        if (lane == 0) { swv[w] = bv; swi[w] = bi; }
        __syncthreads();
        if (tid == 0) {
            double fv = swv[0]; int fi = swi[0];
#pragma unroll
            for (int q = 1; q < 4; ++q)
                if (swv[q] > fv || (swv[q] == fv && swi[q] < fi)) { fv = swv[q]; fi = swi[q]; }
            svals[r] = fv; sidx[r] = fi;
        }
        __syncthreads();
        const int win = sidx[r];
#pragma unroll
        for (int e = 0; e < 8; ++e)
            if (win == e * 256 + tid) ls[e] = -INFINITY;
    }
    __syncthreads();

    const int j = tid >> 2, fg = tid & 3;
    const float th  = tanhf((float)svals[j]);
    const int  idx  = sidx[j];
    const float* xr = Xt + (size_t)idx * FF + fg * 16;
    float* zr = zt + (size_t)t * 4096 + j * 64 + fg * 16;
#pragma unroll
    for (int f = 0; f < 16; f += 4) {
        float4 v = *(const float4*)(xr + f);
        *(float4*)(zr + f) = make_float4(v.x * th, v.y * th, v.z * th, v.w * th);
    }
}

// ---------------------------------------------------------------------------
// K_W: Wz[m][t][i][j] = b_m[i][j] + sum_f W_m[i][f] * z[f][j]
// ---------------------------------------------------------------------------
__global__ __launch_bounds__(256) void wz_kernel(
    const float* __restrict__ zt,
    const float* __restrict__ Wu, const float* __restrict__ bu,
    const float* __restrict__ Wr, const float* __restrict__ br,
    const float* __restrict__ Wh, const float* __restrict__ bh,
    float* __restrict__ Wz)
{
    const int m = blockIdx.x, t = blockIdx.y, tid = threadIdx.x;
    const float* W = (m == 0) ? Wu : (m == 1) ? Wr : Wh;
    const float* b = (m == 0) ? bu : (m == 1) ? br : bh;
    const int j = tid & 63, i0 = (tid >> 6) << 4;

    float zr[64];
    const float* zrow = zt + (size_t)t * 4096 + j * 64;
#pragma unroll
    for (int f = 0; f < 64; f += 4) {
        float4 v = *(const float4*)(zrow + f);
        zr[f] = v.x; zr[f+1] = v.y; zr[f+2] = v.z; zr[f+3] = v.w;
    }
    float* o = Wz + ((size_t)m * TT + t) * 4096;
    for (int i = i0; i < i0 + 16; ++i) {
        float acc = b[i * 64 + j];
#pragma unroll
        for (int f = 0; f < 64; ++f) acc += W[i * 64 + f] * zr[f];
        o[i * 64 + j] = acc;
    }
}

// ---------------------------------------------------------------------------
// K_B: column-separable GRU chain, one Q-column per block.
// ---------------------------------------------------------------------------
__global__ __launch_bounds__(256) void qchain_kernel(
    const float* __restrict__ Q0,
    const float* __restrict__ Uu, const float* __restrict__ Ur, const float* __restrict__ Uh,
    const float* __restrict__ Wz, float* __restrict__ Qseq)
{
    const int j = blockIdx.x, tid = threadIdx.x;
    const int w = tid >> 6, l = tid & 63;
    const int i = (w << 4) + (l & 15);
    const int fq = l >> 4, fb = fq << 4;

    float uu[16], ur[16], uh[16];
#pragma unroll
    for (int e = 0; e < 16; e += 4) {
        float4 a = *(const float4*)(Uu + i * 64 + fb + e);
        uu[e] = a.x; uu[e+1] = a.y; uu[e+2] = a.z; uu[e+3] = a.w;
        float4 c = *(const float4*)(Ur + i * 64 + fb + e);
        ur[e] = c.x; ur[e+1] = c.y; ur[e+2] = c.z; ur[e+3] = c.w;
        float4 d = *(const float4*)(Uh + i * 64 + fb + e);
        uh[e] = d.x; uh[e+1] = d.y; uh[e+2] = d.z; uh[e+3] = d.w;
    }
    __shared__ __align__(16) float q[64];
    __shared__ __align__(16) float rr[64];
    if (tid < 64) q[tid] = Q0[tid * 64 + j];
    __syncthreads();

    const float* WzU = Wz;
    const float* WzR = Wz + (size_t)TT * 4096;
    const float* WzH = Wz + (size_t)2 * TT * 4096;

    for (int t = 0; t < TT; ++t) {
        float q16[16];
#pragma unroll
        for (int e = 0; e < 16; e += 4) {
            f32x4 v = *(const f32x4*)(&q[fb + e]);
            q16[e] = v[0]; q16[e+1] = v[1]; q16[e+2] = v[2]; q16[e+3] = v[3];
        }
        float su = 0.f, sr = 0.f;
#pragma unroll
        for (int e = 0; e < 16; ++e) { su += uu[e] * q16[e]; sr += ur[e] * q16[e]; }
        su += __shfl_xor(su, 16); su += __shfl_xor(su, 32);
        sr += __shfl_xor(sr, 16); sr += __shfl_xor(sr, 32);
        const int off = t * 4096 + i * 64 + j;
        const float u_ = 1.f / (1.f + expf(-(su + WzU[off])));
        const float r_ = 1.f / (1.f + expf(-(sr + WzR[off])));
        if (fq == 0) rr[i] = r_;
        __syncthreads();
        float sh = 0.f;
#pragma unroll
        for (int e = 0; e < 16; e += 4) {
            f32x4 v = *(const f32x4*)(&rr[fb + e]);
            sh += uh[e]   * (v[0] * q16[e]);
            sh += uh[e+1] * (v[1] * q16[e+1]);
            sh += uh[e+2] * (v[2] * q16[e+2]);
            sh += uh[e+3] * (v[3] * q16[e+3]);
        }
        sh += __shfl_xor(sh, 16); sh += __shfl_xor(sh, 32);
        float hv = sh + WzH[off];
        hv = hv > 0.f ? hv : 0.f;
        const float qi = q[i];
        const float qn = (1.f - u_) * qi + u_ * hv;
        __syncthreads();
        if (fq == 0) {
            q[i] = qn;
            Qseq[(size_t)t * 4096 + i * 64 + j] = qn;
        }
        __syncthreads();
    }
}

// ---------------------------------------------------------------------------
// K_C: Ytr[t][j][n] = bf16( sum_f X[t][n][f] * Qseq[t][f][j] )
// LDS transpose -> 16B contiguous global stores.
// ---------------------------------------------------------------------------
__global__ __launch_bounds__(256) void y_kernel(
    const float* __restrict__ X, const float* __restrict__ Qseq,
    unsigned short* __restrict__ Ytr)
{
    const int t = blockIdx.y, tid = threadIdx.x;
    const int n0 = blockIdx.x * 256;
    const int n = n0 + tid;
    __shared__ __align__(16) float Qs[4096];
    __shared__ __align__(16) unsigned short Ys[64][264];  // [j][local n], padded
    for (int c = tid; c < 4096; c += 256) Qs[c] = Qseq[(size_t)t * 4096 + c];
    __syncthreads();

    const float* xr = X + ((size_t)t * NN + n) * FF;
    float y[64];
#pragma unroll
    for (int jj = 0; jj < 64; ++jj) y[jj] = 0.f;
    for (int f4 = 0; f4 < 64; f4 += 4) {
        float4 xv = *(const float4*)(xr + f4);
        float xa[4] = {xv.x, xv.y, xv.z, xv.w};
#pragma unroll
        for (int ff = 0; ff < 4; ++ff) {
            const float xf = xa[ff];
            const float* qr = &Qs[(f4 + ff) << 6];
#pragma unroll
            for (int jj = 0; jj < 64; jj += 4) {
                f32x4 qv = *(const f32x4*)(qr + jj);
                y[jj]   += xf * qv[0];
                y[jj+1] += xf * qv[1];
                y[jj+2] += xf * qv[2];
                y[jj+3] += xf * qv[3];
            }
        }
    }
#pragma unroll
    for (int jj = 0; jj < 64; ++jj) Ys[jj][tid] = f2bf(y[jj]);
    __syncthreads();

    const int j = tid >> 2, nc = (tid & 3) << 6;
    unsigned short* yo = Ytr + (size_t)t * FF * NN + (size_t)j * NN + n0 + nc;
#pragma unroll
    for (int c = 0; c < 8; ++c)
        *(u16x8*)(yo + c * 8) = *(const u16x8*)(&Ys[j][nc + c * 8]);
}

// ---------------------------------------------------------------------------
// K_D: out[t] = relu(A[t] @ Y[t]).  Barrier-free DRAM-page-friendly GEMM:
// tile M=64 x N=64, BK=256, single-buffered 64KB LDS (2 blocks/CU).
// Each wave stages ONLY its own 16 rows (wave-private LDS region) via
// global_load_lds, ONE instr = ONE full 1KB contiguous row segment.
// No __syncthreads at all: per-wave `s_waitcnt vmcnt(0)` + sched_barrier
// fences (rule #18) let 8 waves/CU self-pace and keep HBM continuously
// fed. B (Ytr, XCD-L2-resident) read directly from L2 as fragments.
// A chunk-XOR swizzle via pre-swizzled global source + swizzled ds_read.
// 1024 blocks XCD-grouped.
// ---------------------------------------------------------------------------
__global__ __launch_bounds__(256) void gemm_kernel(
    const float* __restrict__ A, const unsigned short* __restrict__ Ytr,
    float* __restrict__ out)
{
    __shared__ __align__(16) unsigned char Abuf[65536];  // f32 [64 r][1KB]
    const int tid = threadIdx.x;
    const int bid = blockIdx.x;
    const int xcd = bid & 7, li = bid >> 3;          // 8 XCDs x 128 blocks
    const int t = (xcd << 2) + (li >> 5);            // 4 timesteps per XCD
    const int m0 = (li & 31) * 64;
    const int lane = tid & 63, w = tid >> 6;
    const int lr = lane & 15, lq = lane >> 4;

    const float* Ap = A + (size_t)t * NN * NN + (size_t)m0 * NN;
    const unsigned short* Yp = Ytr + (size_t)t * FF * NN;

    const unsigned short* brow[4];
#pragma unroll
    for (int nt = 0; nt < 4; ++nt)
        brow[nt] = Yp + (size_t)((nt << 4) + lr) * NN + (lq << 3);

    f32x4 acc[4];
#pragma unroll
    for (int nt = 0; nt < 4; ++nt) acc[nt] = (f32x4){0.f, 0.f, 0.f, 0.f};

    for (int kt = 0; kt < 8; ++kt) {
        const int kk = kt << 8;
        // STAGE: wave w stages its own rows w*16..w*16+15; 1 instr = 1KB row
#pragma unroll
        for (int q = 0; q < 16; ++q) {
            const int row = (w << 4) + q;
            const float* g = Ap + (size_t)row * NN + kk + ((lane ^ (q & 7)) << 2);
            __builtin_amdgcn_global_load_lds(
                (const __attribute__((address_space(1))) void*)g,
                (__attribute__((address_space(3))) void*)(&Abuf[row << 10]),
                16, 0, 0);
        }
        asm volatile("s_waitcnt vmcnt(0)" ::: "memory");
        __builtin_amdgcn_sched_barrier(0);
        // COMPUTE: 8 sub-steps of K=32
#pragma unroll
        for (int ks = 0; ks < 8; ++ks) {
            const int r = (w << 4) + lr;
            const int c0 = (ks << 3) + (lq << 1);
            const f32x4 a0 = *(const f32x4*)(
                Abuf + (r << 10) + ((c0 ^ (lr & 7)) << 4));
            const f32x4 a1 = *(const f32x4*)(
                Abuf + (r << 10) + (((c0 + 1) ^ (lr & 7)) << 4));
            bf16x8 af;
            af[0] = (__bf16)a0[0]; af[1] = (__bf16)a0[1];
            af[2] = (__bf16)a0[2]; af[3] = (__bf16)a0[3];
            af[4] = (__bf16)a1[0]; af[5] = (__bf16)a1[1];
            af[6] = (__bf16)a1[2]; af[7] = (__bf16)a1[3];
#pragma unroll
            for (int nt = 0; nt < 4; ++nt) {
                const bf16x8 bf = __builtin_bit_cast(bf16x8,
                    *(const uint4*)(brow[nt] + kk + (ks << 5)));
                acc[nt] = __builtin_amdgcn_mfma_f32_16x16x32_bf16(
                    af, bf, acc[nt], 0, 0, 0);
            }
        }
        __builtin_amdgcn_sched_barrier(0);
    }

    // store: D col = lane&15, rows = lq*4 + rg (within wave's 16 rows)
#pragma unroll
    for (int nt = 0; nt < 4; ++nt) {
        const int row0 = m0 + (w << 4) + (lq << 2);
        const int col = (nt << 4) + lr;
#pragma unroll
        for (int rg = 0; rg < 4; ++rg) {
            const float v = acc[nt][rg];
            out[((size_t)t * NN + (row0 + rg)) * FF + col] = v > 0.f ? v : 0.f;
        }
    }
}

// ---------------------------------------------------------------------------
extern "C" void kernel_launch(void* const* d_in, const int* in_sizes, int n_in,
                              void* d_out, int out_size, void* d_ws, size_t ws_size,
                              hipStream_t stream) {
    const float* A      = (const float*)d_in[0];
    const float* X      = (const float*)d_in[1];
    const float* mask   = (const float*)d_in[2];
    const float* Q0     = (const float*)d_in[3];
    const float* scorer = (const float*)d_in[4];
    const float* Wu     = (const float*)d_in[5];
    const float* Uu     = (const float*)d_in[6];
    const float* bu     = (const float*)d_in[7];
    const float* Wr     = (const float*)d_in[8];
    const float* Ur     = (const float*)d_in[9];
    const float* br     = (const float*)d_in[10];
    const float* Wh     = (const float*)d_in[11];
    const float* Uh     = (const float*)d_in[12];
    const float* bh     = (const float*)d_in[13];
    float* out = (float*)d_out;

    float* ws   = (float*)d_ws;
    float* zt   = ws;              // [T][64][64]
    float* Wz   = ws + 131072;     // [3][T][64][64]
    float* Qseq = ws + 524288;     // [T][64][64]
    unsigned short* Ytr = (unsigned short*)(ws + 655360);  // [T][64][2048] bf16

    topk_kernel<<<TT, 256, 0, stream>>>(X, mask, scorer, zt);
    wz_kernel<<<dim3(3, TT), 256, 0, stream>>>(zt, Wu, bu, Wr, br, Wh, bh, Wz);
    qchain_kernel<<<FF, 256, 0, stream>>>(Q0, Uu, Ur, Uh, Wz, Qseq);
    y_kernel<<<dim3(NN / 256, TT), 256, 0, stream>>>(X, Qseq, Ytr);
    gemm_kernel<<<1024, 256, 0, stream>>>(A, Ytr, out);
}

// Round 9
// 349.119 us; speedup vs baseline: 1.1028x; 1.0516x over previous
//
#include <hip/hip_runtime.h>
#include <hip/hip_bf16.h>
#include <math.h>

#define TT 32
#define NN 2048
#define FF 64

typedef float f32x4 __attribute__((ext_vector_type(4)));
typedef __bf16 bf16x8 __attribute__((ext_vector_type(8)));
typedef unsigned short u16x8 __attribute__((ext_vector_type(8)));

__device__ __forceinline__ unsigned short f2bf(float f) {
    __bf16 h = (__bf16)f;
    return __builtin_bit_cast(unsigned short, h);
}

// ---------------------------------------------------------------------------
// K_A: per-timestep scores (fp64) + top-64 (desc, min-index tie-break) +
// z^T[t][j][f] = X[idx_j][f] * tanh(val_j).  grid = T, 256 threads.
// ---------------------------------------------------------------------------
__global__ __launch_bounds__(256) void topk_kernel(
    const float* __restrict__ X, const float* __restrict__ mask,
    const float* __restrict__ scorer, float* __restrict__ zt)
{
    const int t = blockIdx.x, tid = threadIdx.x;
    __shared__ double svals[64];
    __shared__ int    sidx[64];
    __shared__ double swv[4];
    __shared__ int    swi[4];

    float sc[64];
#pragma unroll
    for (int f = 0; f < 64; f += 4) {
        float4 v = *(const float4*)(scorer + f);
        sc[f] = v.x; sc[f+1] = v.y; sc[f+2] = v.z; sc[f+3] = v.w;
    }
    double nrm = 0.0;
#pragma unroll
    for (int f = 0; f < 64; ++f) nrm += (double)sc[f] * (double)sc[f];
    const double inv = 1.0 / sqrt(nrm);

    const float* Xt = X + (size_t)t * NN * FF;
    double ls[8];
#pragma unroll
    for (int e = 0; e < 8; ++e) {
        const int n = e * 256 + tid;
        const float* xr = Xt + (size_t)n * FF;
        double s = 0.0;
#pragma unroll
        for (int f = 0; f < 64; f += 4) {
            float4 v = *(const float4*)(xr + f);
            s += (double)v.x * (double)sc[f]   + (double)v.y * (double)sc[f+1]
               + (double)v.z * (double)sc[f+2] + (double)v.w * (double)sc[f+3];
        }
        ls[e] = s * inv + (double)mask[t * NN + n];
    }

    const int lane = tid & 63, w = tid >> 6;
    for (int r = 0; r < 64; ++r) {
        double bv = ls[0]; int bi = tid;
#pragma unroll
        for (int e = 1; e < 8; ++e) {
            const int n = e * 256 + tid;
            if (ls[e] > bv) { bv = ls[e]; bi = n; }
        }
#pragma unroll
        for (int off = 1; off < 64; off <<= 1) {
            double ov = __shfl_xor(bv, off);
            int    oi = __shfl_xor(bi, off);
            if (ov > bv || (ov == bv && oi < bi)) { bv = ov; bi = oi; }
        }
        if (lane == 0) { swv[w] = bv; swi[w] = bi; }
        __syncthreads();
        if (tid == 0) {
            double fv = swv[0]; int fi = swi[0];
#pragma unroll
            for (int q = 1; q < 4; ++q)
                if (swv[q] > fv || (swv[q] == fv && swi[q] < fi)) { fv = swv[q]; fi = swi[q]; }
            svals[r] = fv; sidx[r] = fi;
        }
        __syncthreads();
        const int win = sidx[r];
#pragma unroll
        for (int e = 0; e < 8; ++e)
            if (win == e * 256 + tid) ls[e] = -INFINITY;
    }
    __syncthreads();

    const int j = tid >> 2, fg = tid & 3;
    const float th  = tanhf((float)svals[j]);
    const int  idx  = sidx[j];
    const float* xr = Xt + (size_t)idx * FF + fg * 16;
    float* zr = zt + (size_t)t * 4096 + j * 64 + fg * 16;
#pragma unroll
    for (int f = 0; f < 16; f += 4) {
        float4 v = *(const float4*)(xr + f);
        *(float4*)(zr + f) = make_float4(v.x * th, v.y * th, v.z * th, v.w * th);
    }
}

// ---------------------------------------------------------------------------
// K_W: Wz[m][t][i][j] = b_m[i][j] + sum_f W_m[i][f] * z[f][j]
// ---------------------------------------------------------------------------
__global__ __launch_bounds__(256) void wz_kernel(
    const float* __restrict__ zt,
    const float* __restrict__ Wu, const float* __restrict__ bu,
    const float* __restrict__ Wr, const float* __restrict__ br,
    const float* __restrict__ Wh, const float* __restrict__ bh,
    float* __restrict__ Wz)
{
    const int m = blockIdx.x, t = blockIdx.y, tid = threadIdx.x;
    const float* W = (m == 0) ? Wu : (m == 1) ? Wr : Wh;
    const float* b = (m == 0) ? bu : (m == 1) ? br : bh;
    const int j = tid & 63, i0 = (tid >> 6) << 4;

    float zr[64];
    const float* zrow = zt + (size_t)t * 4096 + j * 64;
#pragma unroll
    for (int f = 0; f < 64; f += 4) {
        float4 v = *(const float4*)(zrow + f);
        zr[f] = v.x; zr[f+1] = v.y; zr[f+2] = v.z; zr[f+3] = v.w;
    }
    float* o = Wz + ((size_t)m * TT + t) * 4096;
    for (int i = i0; i < i0 + 16; ++i) {
        float acc = b[i * 64 + j];
#pragma unroll
        for (int f = 0; f < 64; ++f) acc += W[i * 64 + f] * zr[f];
        o[i * 64 + j] = acc;
    }
}

// ---------------------------------------------------------------------------
// K_B: column-separable GRU chain, one Q-column per block.
// ---------------------------------------------------------------------------
__global__ __launch_bounds__(256) void qchain_kernel(
    const float* __restrict__ Q0,
    const float* __restrict__ Uu, const float* __restrict__ Ur, const float* __restrict__ Uh,
    const float* __restrict__ Wz, float* __restrict__ Qseq)
{
    const int j = blockIdx.x, tid = threadIdx.x;
    const int w = tid >> 6, l = tid & 63;
    const int i = (w << 4) + (l & 15);
    const int fq = l >> 4, fb = fq << 4;

    float uu[16], ur[16], uh[16];
#pragma unroll
    for (int e = 0; e < 16; e += 4) {
        float4 a = *(const float4*)(Uu + i * 64 + fb + e);
        uu[e] = a.x; uu[e+1] = a.y; uu[e+2] = a.z; uu[e+3] = a.w;
        float4 c = *(const float4*)(Ur + i * 64 + fb + e);
        ur[e] = c.x; ur[e+1] = c.y; ur[e+2] = c.z; ur[e+3] = c.w;
        float4 d = *(const float4*)(Uh + i * 64 + fb + e);
        uh[e] = d.x; uh[e+1] = d.y; uh[e+2] = d.z; uh[e+3] = d.w;
    }
    __shared__ __align__(16) float q[64];
    __shared__ __align__(16) float rr[64];
    if (tid < 64) q[tid] = Q0[tid * 64 + j];
    __syncthreads();

    const float* WzU = Wz;
    const float* WzR = Wz + (size_t)TT * 4096;
    const float* WzH = Wz + (size_t)2 * TT * 4096;

    for (int t = 0; t < TT; ++t) {
        float q16[16];
#pragma unroll
        for (int e = 0; e < 16; e += 4) {
            f32x4 v = *(const f32x4*)(&q[fb + e]);
            q16[e] = v[0]; q16[e+1] = v[1]; q16[e+2] = v[2]; q16[e+3] = v[3];
        }
        float su = 0.f, sr = 0.f;
#pragma unroll
        for (int e = 0; e < 16; ++e) { su += uu[e] * q16[e]; sr += ur[e] * q16[e]; }
        su += __shfl_xor(su, 16); su += __shfl_xor(su, 32);
        sr += __shfl_xor(sr, 16); sr += __shfl_xor(sr, 32);
        const int off = t * 4096 + i * 64 + j;
        const float u_ = 1.f / (1.f + expf(-(su + WzU[off])));
        const float r_ = 1.f / (1.f + expf(-(sr + WzR[off])));
        if (fq == 0) rr[i] = r_;
        __syncthreads();
        float sh = 0.f;
#pragma unroll
        for (int e = 0; e < 16; e += 4) {
            f32x4 v = *(const f32x4*)(&rr[fb + e]);
            sh += uh[e]   * (v[0] * q16[e]);
            sh += uh[e+1] * (v[1] * q16[e+1]);
            sh += uh[e+2] * (v[2] * q16[e+2]);
            sh += uh[e+3] * (v[3] * q16[e+3]);
        }
        sh += __shfl_xor(sh, 16); sh += __shfl_xor(sh, 32);
        float hv = sh + WzH[off];
        hv = hv > 0.f ? hv : 0.f;
        const float qi = q[i];
        const float qn = (1.f - u_) * qi + u_ * hv;
        __syncthreads();
        if (fq == 0) {
            q[i] = qn;
            Qseq[(size_t)t * 4096 + i * 64 + j] = qn;
        }
        __syncthreads();
    }
}

// ---------------------------------------------------------------------------
// K_C: Ytr[t][j][n] = bf16( sum_f X[t][n][f] * Qseq[t][f][j] )
// LDS transpose -> 16B contiguous global stores.
// ---------------------------------------------------------------------------
__global__ __launch_bounds__(256) void y_kernel(
    const float* __restrict__ X, const float* __restrict__ Qseq,
    unsigned short* __restrict__ Ytr)
{
    const int t = blockIdx.y, tid = threadIdx.x;
    const int n0 = blockIdx.x * 256;
    const int n = n0 + tid;
    __shared__ __align__(16) float Qs[4096];
    __shared__ __align__(16) unsigned short Ys[64][264];  // [j][local n], padded
    for (int c = tid; c < 4096; c += 256) Qs[c] = Qseq[(size_t)t * 4096 + c];
    __syncthreads();

    const float* xr = X + ((size_t)t * NN + n) * FF;
    float y[64];
#pragma unroll
    for (int jj = 0; jj < 64; ++jj) y[jj] = 0.f;
    for (int f4 = 0; f4 < 64; f4 += 4) {
        float4 xv = *(const float4*)(xr + f4);
        float xa[4] = {xv.x, xv.y, xv.z, xv.w};
#pragma unroll
        for (int ff = 0; ff < 4; ++ff) {
            const float xf = xa[ff];
            const float* qr = &Qs[(f4 + ff) << 6];
#pragma unroll
            for (int jj = 0; jj < 64; jj += 4) {
                f32x4 qv = *(const f32x4*)(qr + jj);
                y[jj]   += xf * qv[0];
                y[jj+1] += xf * qv[1];
                y[jj+2] += xf * qv[2];
                y[jj+3] += xf * qv[3];
            }
        }
    }
#pragma unroll
    for (int jj = 0; jj < 64; ++jj) Ys[jj][tid] = f2bf(y[jj]);
    __syncthreads();

    const int j = tid >> 2, nc = (tid & 3) << 6;
    unsigned short* yo = Ytr + (size_t)t * FF * NN + (size_t)j * NN + n0 + nc;
#pragma unroll
    for (int c = 0; c < 8; ++c)
        *(u16x8*)(yo + c * 8) = *(const u16x8*)(&Ys[j][nc + c * 8]);
}

// ---------------------------------------------------------------------------
// K_D: out[t] = relu(A[t] @ Y[t]).  Wave-private barrier-free pipelined GEMM:
// tile M=64 x N=64, BK=128, A double-buffered in LDS (2 x 32KB, 2 blk/CU).
// Each wave stages only its own 16 rows: 8 global_load_lds instrs per tile,
// each = 2 rows x 512B sequential. B prefetched ONE TILE AHEAD into named
// register sets B0/B1 (static indexing) so COMPUTE touches only LDS.
// Counted s_waitcnt vmcnt(24) (= next tile's 8 A + 16 B in flight) -- never
// drained to 0 in the loop (T4). XOR chunk-swizzle on A: LDS chunk c of row
// r holds global chunk c^(r&7); read side applies same XOR; bank-checked
// (8 lanes per 4-bank group per ds_read_b128 = optimal). No __syncthreads.
// 1024 blocks XCD-grouped.
// ---------------------------------------------------------------------------
__global__ __launch_bounds__(256) void gemm_kernel(
    const float* __restrict__ A, const unsigned short* __restrict__ Ytr,
    float* __restrict__ out)
{
    __shared__ __align__(16) unsigned char Abuf[2][32768];  // f32 [64 r][512B]
    const int tid = threadIdx.x;
    const int bid = blockIdx.x;
    const int xcd = bid & 7, li = bid >> 3;          // 8 XCDs x 128 blocks
    const int t = (xcd << 2) + (li >> 5);            // 4 timesteps per XCD
    const int m0 = (li & 31) * 64;
    const int lane = tid & 63, w = tid >> 6;
    const int lr = lane & 15, lq = lane >> 4;
    const int sr = lane >> 5, sc = lane & 31;        // staging: row-half, chunk

    const float* Ap = A + (size_t)t * NN * NN + (size_t)m0 * NN;
    const unsigned short* Yp = Ytr + (size_t)t * FF * NN;

    const unsigned short* brow[4];
#pragma unroll
    for (int nt = 0; nt < 4; ++nt)
        brow[nt] = Yp + (size_t)((nt << 4) + lr) * NN + (lq << 3);

    f32x4 acc[4];
#pragma unroll
    for (int nt = 0; nt < 4; ++nt) acc[nt] = (f32x4){0.f, 0.f, 0.f, 0.f};

    uint4 B0[16], B1[16];

    // one instr = 2 rows x 512B; lane i: row r0+(i>>5), chunk i&31, source
    // chunk pre-swizzled by ^(r&7) so LDS chunk c holds global chunk c^(r&7)
#define STAGE(sel, kk)                                                        \
    {                                                                         \
        _Pragma("unroll")                                                     \
        for (int q = 0; q < 8; ++q) {                                         \
            const int r2 = (w << 4) + (q << 1) + sr;                          \
            const float* g = Ap + (size_t)r2 * NN + (kk)                      \
                           + ((sc ^ (r2 & 7)) << 2);                          \
            __builtin_amdgcn_global_load_lds(                                 \
                (const __attribute__((address_space(1))) void*)g,             \
                (__attribute__((address_space(3))) void*)                     \
                    (&Abuf[sel][((w << 4) + (q << 1)) << 9]), 16, 0, 0);      \
        }                                                                     \
    }

#define LOADB(dst, kk)                                                        \
    {                                                                         \
        _Pragma("unroll")                                                     \
        for (int i = 0; i < 16; ++i)                                          \
            dst[i] = *(const uint4*)(brow[i & 3] + (kk) + ((i >> 2) << 5));   \
    }

#define COMPUTE(sel, Breg, kk)                                                \
    {                                                                         \
        _Pragma("unroll")                                                     \
        for (int ks = 0; ks < 4; ++ks) {                                      \
            const int r = (w << 4) + lr;                                      \
            const int c0 = ((ks << 3) + (lq << 1)) ^ (lr & 7);                \
            const int c1 = ((ks << 3) + (lq << 1) + 1) ^ (lr & 7);            \
            const f32x4 a0 = *(const f32x4*)(&Abuf[sel][(r << 9) + (c0 << 4)]); \
            const f32x4 a1 = *(const f32x4*)(&Abuf[sel][(r << 9) + (c1 << 4)]); \
            bf16x8 af;                                                        \
            af[0] = (__bf16)a0[0]; af[1] = (__bf16)a0[1];                     \
            af[2] = (__bf16)a0[2]; af[3] = (__bf16)a0[3];                     \
            af[4] = (__bf16)a1[0]; af[5] = (__bf16)a1[1];                     \
            af[6] = (__bf16)a1[2]; af[7] = (__bf16)a1[3];                     \
            _Pragma("unroll")                                                 \
            for (int nt = 0; nt < 4; ++nt) {                                  \
                const bf16x8 bf = __builtin_bit_cast(bf16x8, Breg[(ks << 2) + nt]); \
                acc[nt] = __builtin_amdgcn_mfma_f32_16x16x32_bf16(            \
                    af, bf, acc[nt], 0, 0, 0);                                \
            }                                                                 \
        }                                                                     \
    }

#define WAIT24 { asm volatile("s_waitcnt vmcnt(24)" ::: "memory");            \
                 __builtin_amdgcn_sched_barrier(0); }

    // prologue: tile 0 in flight
    STAGE(0, 0);
    LOADB(B0, 0);
    // main: 7 full pairs (tiles 0..13), each half stages tile+1
    for (int kp = 0; kp < 7; ++kp) {
        const int kt0 = kp * 2;
        STAGE(1, (kt0 + 1) << 7);
        LOADB(B1, (kt0 + 1) << 7);
        WAIT24;
        COMPUTE(0, B0, kt0 << 7);
        STAGE(0, (kt0 + 2) << 7);
        LOADB(B0, (kt0 + 2) << 7);
        WAIT24;
        COMPUTE(1, B1, (kt0 + 1) << 7);
    }
    // tail: tiles 14, 15
    STAGE(1, 15 << 7);
    LOADB(B1, 15 << 7);
    WAIT24;
    COMPUTE(0, B0, 14 << 7);
    asm volatile("s_waitcnt vmcnt(0)" ::: "memory");
    __builtin_amdgcn_sched_barrier(0);
    COMPUTE(1, B1, 15 << 7);

    // store: D col = lane&15, rows = lq*4 + rg (within wave's 16 rows)
#pragma unroll
    for (int nt = 0; nt < 4; ++nt) {
        const int row0 = m0 + (w << 4) + (lq << 2);
        const int col = (nt << 4) + lr;
#pragma unroll
        for (int rg = 0; rg < 4; ++rg) {
            const float v = acc[nt][rg];
            out[((size_t)t * NN + (row0 + rg)) * FF + col] = v > 0.f ? v : 0.f;
        }
    }
#undef STAGE
#undef LOADB
#undef COMPUTE
#undef WAIT24
}

// ---------------------------------------------------------------------------
extern "C" void kernel_launch(void* const* d_in, const int* in_sizes, int n_in,
                              void* d_out, int out_size, void* d_ws, size_t ws_size,
                              hipStream_t stream) {
    const float* A      = (const float*)d_in[0];
    const float* X      = (const float*)d_in[1];
    const float* mask   = (const float*)d_in[2];
    const float* Q0     = (const float*)d_in[3];
    const float* scorer = (const float*)d_in[4];
    const float* Wu     = (const float*)d_in[5];
    const float* Uu     = (const float*)d_in[6];
    const float* bu     = (const float*)d_in[7];
    const float* Wr     = (const float*)d_in[8];
    const float* Ur     = (const float*)d_in[9];
    const float* br     = (const float*)d_in[10];
    const float* Wh     = (const float*)d_in[11];
    const float* Uh     = (const float*)d_in[12];
    const float* bh     = (const float*)d_in[13];
    float* out = (float*)d_out;

    float* ws   = (float*)d_ws;
    float* zt   = ws;              // [T][64][64]
    float* Wz   = ws + 131072;     // [3][T][64][64]
    float* Qseq = ws + 524288;     // [T][64][64]
    unsigned short* Ytr = (unsigned short*)(ws + 655360);  // [T][64][2048] bf16

    topk_kernel<<<TT, 256, 0, stream>>>(X, mask, scorer, zt);
    wz_kernel<<<dim3(3, TT), 256, 0, stream>>>(zt, Wu, bu, Wr, br, Wh, bh, Wz);
    qchain_kernel<<<FF, 256, 0, stream>>>(Q0, Uu, Ur, Uh, Wz, Qseq);
    y_kernel<<<dim3(NN / 256, TT), 256, 0, stream>>>(X, Qseq, Ytr);
    gemm_kernel<<<1024, 256, 0, stream>>>(A, Ytr, out);
}

// Round 10
// 312.488 us; speedup vs baseline: 1.2321x; 1.1172x over previous
//
#include <hip/hip_runtime.h>
#include <hip/hip_bf16.h>
#include <math.h>

#define TT 32
#define NN 2048
#define FF 64

typedef float f32x4 __attribute__((ext_vector_type(4)));
typedef __bf16 bf16x8 __attribute__((ext_vector_type(8)));
typedef unsigned short u16x8 __attribute__((ext_vector_type(8)));

__device__ __forceinline__ unsigned short f2bf(float f) {
    __bf16 h = (__bf16)f;
    return __builtin_bit_cast(unsigned short, h);
}

// ---------------------------------------------------------------------------
// K_A: per-timestep scores (fp64) + top-64 (desc, min-index tie-break) +
// z^T[t][j][f] = X[idx_j][f] * tanh(val_j).  grid = T, 256 threads.
// ---------------------------------------------------------------------------
__global__ __launch_bounds__(256) void topk_kernel(
    const float* __restrict__ X, const float* __restrict__ mask,
    const float* __restrict__ scorer, float* __restrict__ zt)
{
    const int t = blockIdx.x, tid = threadIdx.x;
    __shared__ double svals[64];
    __shared__ int    sidx[64];
    __shared__ double swv[4];
    __shared__ int    swi[4];

    float sc[64];
#pragma unroll
    for (int f = 0; f < 64; f += 4) {
        float4 v = *(const float4*)(scorer + f);
        sc[f] = v.x; sc[f+1] = v.y; sc[f+2] = v.z; sc[f+3] = v.w;
    }
    double nrm = 0.0;
#pragma unroll
    for (int f = 0; f < 64; ++f) nrm += (double)sc[f] * (double)sc[f];
    const double inv = 1.0 / sqrt(nrm);

    const float* Xt = X + (size_t)t * NN * FF;
    double ls[8];
#pragma unroll
    for (int e = 0; e < 8; ++e) {
        const int n = e * 256 + tid;
        const float* xr = Xt + (size_t)n * FF;
        double s = 0.0;
#pragma unroll
        for (int f = 0; f < 64; f += 4) {
            float4 v = *(const float4*)(xr + f);
            s += (double)v.x * (double)sc[f]   + (double)v.y * (double)sc[f+1]
               + (double)v.z * (double)sc[f+2] + (double)v.w * (double)sc[f+3];
        }
        ls[e] = s * inv + (double)mask[t * NN + n];
    }

    const int lane = tid & 63, w = tid >> 6;
    for (int r = 0; r < 64; ++r) {
        double bv = ls[0]; int bi = tid;
#pragma unroll
        for (int e = 1; e < 8; ++e) {
            const int n = e * 256 + tid;
            if (ls[e] > bv) { bv = ls[e]; bi = n; }
        }
#pragma unroll
        for (int off = 1; off < 64; off <<= 1) {
            double ov = __shfl_xor(bv, off);
            int    oi = __shfl_xor(bi, off);
            if (ov > bv || (ov == bv && oi < bi)) { bv = ov; bi = oi; }
        }
        if (lane == 0) { swv[w] = bv; swi[w] = bi; }
        __syncthreads();
        if (tid == 0) {
            double fv = swv[0]; int fi = swi[0];
#pragma unroll
            for (int q = 1; q < 4; ++q)
                if (swv[q] > fv || (swv[q] == fv && swi[q] < fi)) { fv = swv[q]; fi = swi[q]; }
            svals[r] = fv; sidx[r] = fi;
        }
        __syncthreads();
        const int win = sidx[r];
#pragma unroll
        for (int e = 0; e < 8; ++e)
            if (win == e * 256 + tid) ls[e] = -INFINITY;
    }
    __syncthreads();

    const int j = tid >> 2, fg = tid & 3;
    const float th  = tanhf((float)svals[j]);
    const int  idx  = sidx[j];
    const float* xr = Xt + (size_t)idx * FF + fg * 16;
    float* zr = zt + (size_t)t * 4096 + j * 64 + fg * 16;
#pragma unroll
    for (int f = 0; f < 16; f += 4) {
        float4 v = *(const float4*)(xr + f);
        *(float4*)(zr + f) = make_float4(v.x * th, v.y * th, v.z * th, v.w * th);
    }
}

// ---------------------------------------------------------------------------
// K_W: Wz[m][t][i][j] = b_m[i][j] + sum_f W_m[i][f] * z[f][j]
// ---------------------------------------------------------------------------
__global__ __launch_bounds__(256) void wz_kernel(
    const float* __restrict__ zt,
    const float* __restrict__ Wu, const float* __restrict__ bu,
    const float* __restrict__ Wr, const float* __restrict__ br,
    const float* __restrict__ Wh, const float* __restrict__ bh,
    float* __restrict__ Wz)
{
    const int m = blockIdx.x, t = blockIdx.y, tid = threadIdx.x;
    const float* W = (m == 0) ? Wu : (m == 1) ? Wr : Wh;
    const float* b = (m == 0) ? bu : (m == 1) ? br : bh;
    const int j = tid & 63, i0 = (tid >> 6) << 4;

    float zr[64];
    const float* zrow = zt + (size_t)t * 4096 + j * 64;
#pragma unroll
    for (int f = 0; f < 64; f += 4) {
        float4 v = *(const float4*)(zrow + f);
        zr[f] = v.x; zr[f+1] = v.y; zr[f+2] = v.z; zr[f+3] = v.w;
    }
    float* o = Wz + ((size_t)m * TT + t) * 4096;
    for (int i = i0; i < i0 + 16; ++i) {
        float acc = b[i * 64 + j];
#pragma unroll
        for (int f = 0; f < 64; ++f) acc += W[i * 64 + f] * zr[f];
        o[i * 64 + j] = acc;
    }
}

// ---------------------------------------------------------------------------
// K_B: column-separable GRU chain, one Q-column per block.
// ---------------------------------------------------------------------------
__global__ __launch_bounds__(256) void qchain_kernel(
    const float* __restrict__ Q0,
    const float* __restrict__ Uu, const float* __restrict__ Ur, const float* __restrict__ Uh,
    const float* __restrict__ Wz, float* __restrict__ Qseq)
{
    const int j = blockIdx.x, tid = threadIdx.x;
    const int w = tid >> 6, l = tid & 63;
    const int i = (w << 4) + (l & 15);
    const int fq = l >> 4, fb = fq << 4;

    float uu[16], ur[16], uh[16];
#pragma unroll
    for (int e = 0; e < 16; e += 4) {
        float4 a = *(const float4*)(Uu + i * 64 + fb + e);
        uu[e] = a.x; uu[e+1] = a.y; uu[e+2] = a.z; uu[e+3] = a.w;
        float4 c = *(const float4*)(Ur + i * 64 + fb + e);
        ur[e] = c.x; ur[e+1] = c.y; ur[e+2] = c.z; ur[e+3] = c.w;
        float4 d = *(const float4*)(Uh + i * 64 + fb + e);
        uh[e] = d.x; uh[e+1] = d.y; uh[e+2] = d.z; uh[e+3] = d.w;
    }
    __shared__ __align__(16) float q[64];
    __shared__ __align__(16) float rr[64];
    if (tid < 64) q[tid] = Q0[tid * 64 + j];
    __syncthreads();

    const float* WzU = Wz;
    const float* WzR = Wz + (size_t)TT * 4096;
    const float* WzH = Wz + (size_t)2 * TT * 4096;

    for (int t = 0; t < TT; ++t) {
        float q16[16];
#pragma unroll
        for (int e = 0; e < 16; e += 4) {
            f32x4 v = *(const f32x4*)(&q[fb + e]);
            q16[e] = v[0]; q16[e+1] = v[1]; q16[e+2] = v[2]; q16[e+3] = v[3];
        }
        float su = 0.f, sr = 0.f;
#pragma unroll
        for (int e = 0; e < 16; ++e) { su += uu[e] * q16[e]; sr += ur[e] * q16[e]; }
        su += __shfl_xor(su, 16); su += __shfl_xor(su, 32);
        sr += __shfl_xor(sr, 16); sr += __shfl_xor(sr, 32);
        const int off = t * 4096 + i * 64 + j;
        const float u_ = 1.f / (1.f + expf(-(su + WzU[off])));
        const float r_ = 1.f / (1.f + expf(-(sr + WzR[off])));
        if (fq == 0) rr[i] = r_;
        __syncthreads();
        float sh = 0.f;
#pragma unroll
        for (int e = 0; e < 16; e += 4) {
            f32x4 v = *(const f32x4*)(&rr[fb + e]);
            sh += uh[e]   * (v[0] * q16[e]);
            sh += uh[e+1] * (v[1] * q16[e+1]);
            sh += uh[e+2] * (v[2] * q16[e+2]);
            sh += uh[e+3] * (v[3] * q16[e+3]);
        }
        sh += __shfl_xor(sh, 16); sh += __shfl_xor(sh, 32);
        float hv = sh + WzH[off];
        hv = hv > 0.f ? hv : 0.f;
        const float qi = q[i];
        const float qn = (1.f - u_) * qi + u_ * hv;
        __syncthreads();
        if (fq == 0) {
            q[i] = qn;
            Qseq[(size_t)t * 4096 + i * 64 + j] = qn;
        }
        __syncthreads();
    }
}

// ---------------------------------------------------------------------------
// K_C: Ytr[t][j][n] = bf16( sum_f X[t][n][f] * Qseq[t][f][j] )
// LDS transpose -> 16B contiguous global stores.
// ---------------------------------------------------------------------------
__global__ __launch_bounds__(256) void y_kernel(
    const float* __restrict__ X, const float* __restrict__ Qseq,
    unsigned short* __restrict__ Ytr)
{
    const int t = blockIdx.y, tid = threadIdx.x;
    const int n0 = blockIdx.x * 256;
    const int n = n0 + tid;
    __shared__ __align__(16) float Qs[4096];
    __shared__ __align__(16) unsigned short Ys[64][264];  // [j][local n], padded
    for (int c = tid; c < 4096; c += 256) Qs[c] = Qseq[(size_t)t * 4096 + c];
    __syncthreads();

    const float* xr = X + ((size_t)t * NN + n) * FF;
    float y[64];
#pragma unroll
    for (int jj = 0; jj < 64; ++jj) y[jj] = 0.f;
    for (int f4 = 0; f4 < 64; f4 += 4) {
        float4 xv = *(const float4*)(xr + f4);
        float xa[4] = {xv.x, xv.y, xv.z, xv.w};
#pragma unroll
        for (int ff = 0; ff < 4; ++ff) {
            const float xf = xa[ff];
            const float* qr = &Qs[(f4 + ff) << 6];
#pragma unroll
            for (int jj = 0; jj < 64; jj += 4) {
                f32x4 qv = *(const f32x4*)(qr + jj);
                y[jj]   += xf * qv[0];
                y[jj+1] += xf * qv[1];
                y[jj+2] += xf * qv[2];
                y[jj+3] += xf * qv[3];
            }
        }
    }
#pragma unroll
    for (int jj = 0; jj < 64; ++jj) Ys[jj][tid] = f2bf(y[jj]);
    __syncthreads();

    const int j = tid >> 2, nc = (tid & 3) << 6;
    unsigned short* yo = Ytr + (size_t)t * FF * NN + (size_t)j * NN + n0 + nc;
#pragma unroll
    for (int c = 0; c < 8; ++c)
        *(u16x8*)(yo + c * 8) = *(const u16x8*)(&Ys[j][nc + c * 8]);
}

// ---------------------------------------------------------------------------
// K_D: out[t] = relu(A[t] @ Y[t]).  High-occupancy small-tile MFMA GEMM:
// tile M=64 x N=64, BK=64, SINGLE-buffered 24KB LDS -> 4+ blocks/CU
// (grid 1024, 4/CU resident). 4 independent blocks per CU have
// uncorrelated barrier phases -> HBM stays fed while any one block
// drains/computes (fix for the synchronized vmcnt(0) hole at 2 blk/CU).
// A staged f32 via global_load_lds (wave-private rows), B staged bf16 in
// LDS (shared; avoids the 2GB redundant L2 B-traffic of direct-B).
// Chunk-XOR swizzle on both sides (rule #21). R3-proven 2-barrier sync.
// ---------------------------------------------------------------------------
__global__ __launch_bounds__(256, 4) void gemm_kernel(
    const float* __restrict__ A, const unsigned short* __restrict__ Ytr,
    float* __restrict__ out)
{
    __shared__ __align__(16) unsigned char Abuf[16384];  // f32 [64 r][256B]
    __shared__ __align__(16) unsigned char Bbuf[8192];   // bf16 [64 j][128B]
    const int tid = threadIdx.x;
    const int bid = blockIdx.x;
    const int xcd = bid & 7, li = bid >> 3;          // 8 XCDs x 128 blocks
    const int t = (xcd << 2) + (li >> 5);            // 4 timesteps per XCD
    const int m0 = (li & 31) * 64;
    const int lane = tid & 63, w = tid >> 6;
    const int lr = lane & 15, lq = lane >> 4;

    const float* Ap = A + (size_t)t * NN * NN + (size_t)m0 * NN;
    const unsigned short* Yp = Ytr + (size_t)t * FF * NN;

    f32x4 acc[4];
#pragma unroll
    for (int nt = 0; nt < 4; ++nt) acc[nt] = (f32x4){0.f, 0.f, 0.f, 0.f};

    for (int kt = 0; kt < 32; ++kt) {
        const int kk = kt << 6;
        // STAGE A: wave w stages its own rows w*16+q*4+(lane>>4); one instr
        // = 4 rows x 256B. Global chunk pre-swizzled by ^(row&7).
#pragma unroll
        for (int q = 0; q < 4; ++q) {
            const int row = (w << 4) + (q << 2) + lq;
            const float* g = Ap + (size_t)row * NN + kk + ((lr ^ (row & 7)) << 2);
            __builtin_amdgcn_global_load_lds(
                (const __attribute__((address_space(1))) void*)g,
                (__attribute__((address_space(3))) void*)
                    (&Abuf[((w << 4) + (q << 2)) << 8]), 16, 0, 0);
        }
        // STAGE B: j = w*16+q*8+(lane>>3), chunk (lane&7)^(j&7); instr = 8 j x 128B
#pragma unroll
        for (int q = 0; q < 2; ++q) {
            const int j = (w << 4) + (q << 3) + (lane >> 3);
            const unsigned short* g = Yp + (size_t)j * NN + kk
                                    + (((lane & 7) ^ (j & 7)) << 3);
            __builtin_amdgcn_global_load_lds(
                (const __attribute__((address_space(1))) void*)g,
                (__attribute__((address_space(3))) void*)
                    (&Bbuf[((w << 4) + (q << 3)) << 7]), 16, 0, 0);
        }
        __syncthreads();   // compiler drains vmcnt before barrier
        // COMPUTE: wave w -> rows w*16..w*16+15, 2 k-sub x 4 n-tiles
#pragma unroll
        for (int ks = 0; ks < 2; ++ks) {
            const int r = (w << 4) + lr;
            const int c0 = ((ks << 3) + (lq << 1)) ^ (lr & 7);
            const int c1 = ((ks << 3) + (lq << 1) + 1) ^ (lr & 7);
            const f32x4 a0 = *(const f32x4*)(&Abuf[(r << 8) + (c0 << 4)]);
            const f32x4 a1 = *(const f32x4*)(&Abuf[(r << 8) + (c1 << 4)]);
            bf16x8 af;
            af[0] = (__bf16)a0[0]; af[1] = (__bf16)a0[1];
            af[2] = (__bf16)a0[2]; af[3] = (__bf16)a0[3];
            af[4] = (__bf16)a1[0]; af[5] = (__bf16)a1[1];
            af[6] = (__bf16)a1[2]; af[7] = (__bf16)a1[3];
#pragma unroll
            for (int nt = 0; nt < 4; ++nt) {
                const int j = (nt << 4) + lr;
                const int x = ((ks << 2) + lq) ^ (j & 7);
                const bf16x8 bf = *(const bf16x8*)(&Bbuf[(j << 7) + (x << 4)]);
                acc[nt] = __builtin_amdgcn_mfma_f32_16x16x32_bf16(
                    af, bf, acc[nt], 0, 0, 0);
            }
        }
        __syncthreads();   // protect buffer overwrite
    }

    // store: D col = lane&15, rows = lq*4 + rg (within wave's 16 rows)
#pragma unroll
    for (int nt = 0; nt < 4; ++nt) {
        const int row0 = m0 + (w << 4) + (lq << 2);
        const int col = (nt << 4) + lr;
#pragma unroll
        for (int rg = 0; rg < 4; ++rg) {
            const float v = acc[nt][rg];
            out[((size_t)t * NN + (row0 + rg)) * FF + col] = v > 0.f ? v : 0.f;
        }
    }
}

// ---------------------------------------------------------------------------
extern "C" void kernel_launch(void* const* d_in, const int* in_sizes, int n_in,
                              void* d_out, int out_size, void* d_ws, size_t ws_size,
                              hipStream_t stream) {
    const float* A      = (const float*)d_in[0];
    const float* X      = (const float*)d_in[1];
    const float* mask   = (const float*)d_in[2];
    const float* Q0     = (const float*)d_in[3];
    const float* scorer = (const float*)d_in[4];
    const float* Wu     = (const float*)d_in[5];
    const float* Uu     = (const float*)d_in[6];
    const float* bu     = (const float*)d_in[7];
    const float* Wr     = (const float*)d_in[8];
    const float* Ur     = (const float*)d_in[9];
    const float* br     = (const float*)d_in[10];
    const float* Wh     = (const float*)d_in[11];
    const float* Uh     = (const float*)d_in[12];
    const float* bh     = (const float*)d_in[13];
    float* out = (float*)d_out;

    float* ws   = (float*)d_ws;
    float* zt   = ws;              // [T][64][64]
    float* Wz   = ws + 131072;     // [3][T][64][64]
    float* Qseq = ws + 524288;     // [T][64][64]
    unsigned short* Ytr = (unsigned short*)(ws + 655360);  // [T][64][2048] bf16

    topk_kernel<<<TT, 256, 0, stream>>>(X, mask, scorer, zt);
    wz_kernel<<<dim3(3, TT), 256, 0, stream>>>(zt, Wu, bu, Wr, br, Wh, bh, Wz);
    qchain_kernel<<<FF, 256, 0, stream>>>(Q0, Uu, Ur, Uh, Wz, Qseq);
    y_kernel<<<dim3(NN / 256, TT), 256, 0, stream>>>(X, Qseq, Ytr);
    gemm_kernel<<<1024, 256, 0, stream>>>(A, Ytr, out);
}